// Round 6
// baseline (4944.705 us; speedup 1.0000x reference)
//
#include <hip/hip_runtime.h>
#include <hip/hip_bf16.h>

#define B_  64
#define T_  1024
#define D_  512
#define H_  1024
#define G4H (4 * H_)
#define NWG 256

typedef __attribute__((ext_vector_type(8))) short bf16x8;
typedef __attribute__((ext_vector_type(4))) float f32x4;

__device__ __forceinline__ short f2bf(float f) {
    union { float f; unsigned int u; } v; v.f = f;
    unsigned int r = v.u + 0x7FFFu + ((v.u >> 16) & 1u);  // RNE
    return (short)(r >> 16);
}
__device__ __forceinline__ float sigmoid_f(float x) { return 1.0f / (1.0f + __expf(-x)); }
__device__ __forceinline__ float tanh_f(float x) {
    float ax = fabsf(x);
    float e  = __expf(-2.0f * ax);
    return copysignf((1.0f - e) / (1.0f + e), x);
}

// 16B device-coherent load (2 x 8B agent-scope relaxed atomics, serviced at
// the coherence point; no cache-walk fences needed).
__device__ __forceinline__ bf16x8 load_h16(const short* p) {
    union { bf16x8 v; unsigned long long q[2]; } u;
    u.q[0] = __hip_atomic_load((const unsigned long long*)p,
                               __ATOMIC_RELAXED, __HIP_MEMORY_SCOPE_AGENT);
    u.q[1] = __hip_atomic_load((const unsigned long long*)p + 1,
                               __ATOMIC_RELAXED, __HIP_MEMORY_SCOPE_AGENT);
    return u.v;
}

// R6: (a) counter barrier — arrival is ONE memory-side atomic add per WG on a
// single per-group line; wait is ONE poller (tid0) per WG. Kills the R5 poll
// storm (16384 spinning lanes on 256 lines -> 256 lanes on 4 lines) that
// congested the IC port the critical-path h traffic needs. (b) x-part
// (loads+f2bf+MFMA) and y-store execute AFTER the signal, overlapping flag
// propagation and other WGs' skew; post-barrier serial region is now only
// h-load -> h-MFMA -> reduce -> activations -> h-store -> drain -> signal.
__global__ void __launch_bounds__(256, 1)
lstm_persistent(const float* __restrict__ x,     // [B,T,D]
                const float* __restrict__ Wx,    // [D,4H]
                const float* __restrict__ Wh,    // [H,4H]
                const float* __restrict__ bias,  // [4H] (i,f,g,o)
                float* __restrict__ y,           // [B,T,H]
                short* __restrict__ h_buf,       // ws: [2][B][H] bf16
                int* __restrict__ cnt)           // ws: [4] group counters, 64B apart
{
    const int wg   = blockIdx.x;
    const int tid  = threadIdx.x;
    const int lane = tid & 63;
    const int wv   = tid >> 6;
    // Round-robin dispatch: group bt's 64 WGs land on XCD pair {2bt, 2bt+1}
    // (locality heuristic only; correctness is scope-based, mapping-agnostic).
    const int bt   = (wg >> 1) & 3;               // batch tile 0..3
    const int jt   = ((wg & 1) << 5) | (wg >> 3); // hidden tile 0..63
    const int j0   = jt * 16;

    const int c    = lane & 15;         // A-row (batch) / B-col within tile
    const int kblk = lane >> 4;         // k-block (8 contiguous k)
    const int b_a  = bt * 16 + c;       // global batch for A-frags
    const int kh0  = wv * 256;          // wave's K-slice of H
    const int kx0  = wv * 128;          // wave's K-slice of D

    __shared__ bf16x8 hw[4][4][8][64];  // 128 KB: [wv][gate][ks][lane]
    __shared__ float  gbuf[4][16][67];  // 17 KB partial-gate tiles

    // ---- prologue: h-weights -> LDS (each thread fills/reads its own slot)
#pragma unroll
    for (int g = 0; g < 4; ++g)
#pragma unroll
        for (int ks = 0; ks < 8; ++ks) {
            bf16x8 tf;
#pragma unroll
            for (int e = 0; e < 8; ++e)
                tf[e] = f2bf(Wh[(size_t)(kh0 + ks * 32 + kblk * 8 + e) * G4H
                                + g * H_ + j0 + c]);
            hw[wv][g][ks][lane] = tf;
        }

    // ---- x-weights -> registers (64 VGPRs), pinned vs rematerialization
    bf16x8 wxf[4][4];
#pragma unroll
    for (int g = 0; g < 4; ++g)
#pragma unroll
        for (int ks = 0; ks < 4; ++ks) {
            bf16x8 tf;
#pragma unroll
            for (int e = 0; e < 8; ++e)
                tf[e] = f2bf(Wx[(size_t)(kx0 + ks * 32 + kblk * 8 + e) * G4H
                                + g * H_ + j0 + c]);
            wxf[g][ks] = tf;
        }
#pragma unroll
    for (int g = 0; g < 4; ++g)
#pragma unroll
        for (int ks = 0; ks < 4; ++ks)
            asm volatile("" : "+v"(wxf[g][ks]));   // opaque: cannot re-load

    // ---- epilogue mapping: thread -> one (batch eb, hidden ej)
    const int eb = tid >> 4;
    const int ej = tid & 15;
    const float bi  = bias[0 * H_ + j0 + ej];
    const float bfv = bias[1 * H_ + j0 + ej];
    const float bg  = bias[2 * H_ + j0 + ej];
    const float bo  = bias[3 * H_ + j0 + ej];
    const int b_glob = bt * 16 + eb;
    const int j_glob = j0 + ej;

    float cstate = 0.0f;
    int* const mycnt = cnt + bt * 16;   // 64B-spaced group counter

    // ---- x-part for t=0 (h-independent), into the running accumulator
    f32x4 accx[4] = {{0.f,0.f,0.f,0.f},{0.f,0.f,0.f,0.f},
                     {0.f,0.f,0.f,0.f},{0.f,0.f,0.f,0.f}};
    {
        const float* xr = x + ((size_t)b_a * T_ + 0) * D_ + kx0 + kblk * 8;
#pragma unroll
        for (int ks = 0; ks < 4; ++ks) {
            f32x4 lo = *(const f32x4*)(xr + ks * 32);
            f32x4 hi = *(const f32x4*)(xr + ks * 32 + 4);
            bf16x8 xa;
#pragma unroll
            for (int e = 0; e < 4; ++e) { xa[e] = f2bf(lo[e]); xa[e+4] = f2bf(hi[e]); }
#pragma unroll
            for (int g = 0; g < 4; ++g)
                accx[g] = __builtin_amdgcn_mfma_f32_16x16x32_bf16(xa, wxf[g][ks], accx[g], 0, 0, 0);
        }
    }

#pragma unroll 1
    for (int t = 0; t < T_; ++t) {
        // ---- wait: group counter reaches 64*t (one poller per WG) ----
        if (t > 0) {
            if (tid == 0)
                while (__hip_atomic_load(mycnt, __ATOMIC_RELAXED,
                                         __HIP_MEMORY_SCOPE_AGENT) < (t << 6)) {}
            __syncthreads();
        }

        // ---- h-phase: 8 x 16B coherent loads, then 32 MFMAs (4 chains) ----
        const short* hb = h_buf + (t & 1) * (B_ * H_)
                        + (size_t)b_a * H_ + kh0 + kblk * 8;
        bf16x8 ha[8];
#pragma unroll
        for (int ks = 0; ks < 8; ++ks)
            ha[ks] = load_h16(hb + ks * 32);
#pragma unroll
        for (int ks = 0; ks < 8; ++ks) {
            bf16x8 w0 = hw[wv][0][ks][lane];
            bf16x8 w1 = hw[wv][1][ks][lane];
            bf16x8 w2 = hw[wv][2][ks][lane];
            bf16x8 w3 = hw[wv][3][ks][lane];
            accx[0] = __builtin_amdgcn_mfma_f32_16x16x32_bf16(ha[ks], w0, accx[0], 0, 0, 0);
            accx[1] = __builtin_amdgcn_mfma_f32_16x16x32_bf16(ha[ks], w1, accx[1], 0, 0, 0);
            accx[2] = __builtin_amdgcn_mfma_f32_16x16x32_bf16(ha[ks], w2, accx[2], 0, 0, 0);
            accx[3] = __builtin_amdgcn_mfma_f32_16x16x32_bf16(ha[ks], w3, accx[3], 0, 0, 0);
        }

        // ---- partials -> LDS (D layout: col = lane&15, row = kblk*4 + r) ----
#pragma unroll
        for (int g = 0; g < 4; ++g)
#pragma unroll
            for (int r = 0; r < 4; ++r)
                gbuf[wv][kblk * 4 + r][g * 16 + c] = accx[g][r];
        __syncthreads();

        // ---- reduce 4 wave-partials + activations ----
        float gi = ((gbuf[0][eb][ 0+ej] + gbuf[1][eb][ 0+ej])
                  + (gbuf[2][eb][ 0+ej] + gbuf[3][eb][ 0+ej])) + bi;
        float gf = ((gbuf[0][eb][16+ej] + gbuf[1][eb][16+ej])
                  + (gbuf[2][eb][16+ej] + gbuf[3][eb][16+ej])) + bfv;
        float gg = ((gbuf[0][eb][32+ej] + gbuf[1][eb][32+ej])
                  + (gbuf[2][eb][32+ej] + gbuf[3][eb][32+ej])) + bg;
        float go = ((gbuf[0][eb][48+ej] + gbuf[1][eb][48+ej])
                  + (gbuf[2][eb][48+ej] + gbuf[3][eb][48+ej])) + bo;

        float I = sigmoid_f(gi);
        float F = sigmoid_f(gf);
        float G = tanh_f(gg);
        float O = sigmoid_f(go);
        cstate = F * cstate + I * G;
        float hval = O * tanh_f(cstate);

        // ---- h sc-store (8B packed per 4 lanes) -> drain -> signal ----
        unsigned int mybf = (unsigned int)(unsigned short)f2bf(hval);
        unsigned int p01  = mybf | (((unsigned int)__shfl_xor((int)mybf, 1, 64)) << 16);
        unsigned int p23  = (unsigned int)__shfl_xor((int)p01, 2, 64);
        if ((ej & 3) == 0) {
            unsigned long long pk = (unsigned long long)p01
                                  | ((unsigned long long)p23 << 32);
            unsigned long long* hp = (unsigned long long*)
                (h_buf + ((t + 1) & 1) * (B_ * H_) + (size_t)b_glob * H_ + j_glob);
            __hip_atomic_store(hp, pk, __ATOMIC_RELAXED, __HIP_MEMORY_SCOPE_AGENT);
        }
        // __syncthreads drains vmcnt(0) in every wave: all h sc-stores acked
        // at the coherence point before tid0's arrival add issues.
        __syncthreads();
        if (tid == 0) {
            int old = __hip_atomic_fetch_add(mycnt, 1, __ATOMIC_RELAXED,
                                             __HIP_MEMORY_SCOPE_AGENT);
            (void)old;
        }

        // ---- off-critical-path tail: y store + next step's x-part ----
        y[((size_t)b_glob * T_ + t) * H_ + j_glob] = hval;   // 64B / 16 lanes

#pragma unroll
        for (int g = 0; g < 4; ++g)
            accx[g] = (f32x4){0.f,0.f,0.f,0.f};
        if (t + 1 < T_) {
            const float* xr = x + ((size_t)b_a * T_ + (t + 1)) * D_ + kx0 + kblk * 8;
#pragma unroll
            for (int ks = 0; ks < 4; ++ks) {
                f32x4 lo = *(const f32x4*)(xr + ks * 32);
                f32x4 hi = *(const f32x4*)(xr + ks * 32 + 4);
                bf16x8 xa;
#pragma unroll
                for (int e = 0; e < 4; ++e) { xa[e] = f2bf(lo[e]); xa[e+4] = f2bf(hi[e]); }
#pragma unroll
                for (int g = 0; g < 4; ++g)
                    accx[g] = __builtin_amdgcn_mfma_f32_16x16x32_bf16(xa, wxf[g][ks], accx[g], 0, 0, 0);
            }
        }
    }
}

extern "C" void kernel_launch(void* const* d_in, const int* in_sizes, int n_in,
                              void* d_out, int out_size, void* d_ws, size_t ws_size,
                              hipStream_t stream)
{
    const float* x    = (const float*)d_in[0];
    const float* Wx   = (const float*)d_in[1];
    const float* Wh   = (const float*)d_in[2];
    const float* bias = (const float*)d_in[3];
    float* y = (float*)d_out;

    char* ws = (char*)d_ws;
    const size_t h_bytes = (size_t)2 * B_ * H_ * sizeof(short);   // 256 KB
    short* h_buf = (short*)ws;
    int*   cnt   = (int*)(ws + h_bytes);                           // 4x 64B-spaced

    // Re-init every call: h0 = 0; counters MUST be zeroed (stale counts from
    // a prior replay would let pollers race past the barrier).
    hipMemsetAsync(d_ws, 0, h_bytes + 256, stream);

    lstm_persistent<<<dim3(NWG), dim3(256), 0, stream>>>(
        x, Wx, Wh, bias, y, h_buf, cnt);
}

// Round 7
// 4538.409 us; speedup vs baseline: 1.0895x; 1.0895x over previous
//
#include <hip/hip_runtime.h>
#include <hip/hip_bf16.h>

#define B_  64
#define T_  1024
#define D_  512
#define H_  1024
#define G4H (4 * H_)
#define NWG 256
#define DP  4                      // h ring depth
#define SENTQ 0x7FC07FC07FC07FC0ull  // bf16 NaN x4: unreachable, |h|<1 always

typedef __attribute__((ext_vector_type(8))) short bf16x8;
typedef __attribute__((ext_vector_type(4))) float f32x4;

__device__ __forceinline__ short f2bf(float f) {
    union { float f; unsigned int u; } v; v.f = f;
    unsigned int r = v.u + 0x7FFFu + ((v.u >> 16) & 1u);  // RNE
    return (short)(r >> 16);
}
__device__ __forceinline__ float sigmoid_f(float x) { return 1.0f / (1.0f + __expf(-x)); }
__device__ __forceinline__ float tanh_f(float x) {
    float ax = fabsf(x);
    float e  = __expf(-2.0f * ax);
    return copysignf((1.0f - e) / (1.0f + e), x);
}

__device__ __forceinline__ unsigned long long aload(const unsigned long long* p) {
    return __hip_atomic_load(p, __ATOMIC_RELAXED, __HIP_MEMORY_SCOPE_AGENT);
}

// init: buf0 = 0.0 (this IS h_0), buf1..3 = sentinel
__global__ void init_hbuf(unsigned int* p) {
    int i = blockIdx.x * 256 + threadIdx.x;        // 131072 u32 = 4*B*H shorts
    p[i] = (i < (B_ * H_ / 2)) ? 0u : 0x7FC07FC0u;
}

// R7: dataflow sync — the h data IS the flag. Depth-4 ring; consumers poll
// their needed qwords until != NaN-sentinel (h in (-1,1), NaN unreachable).
// Producer's packed 8B h-store is the signal: no drain-before-signal, no
// counter, no barrier. Serial chain per step = ONE IC trip (store->visible)
// + poll quantization + compute, vs R6's four dependent IC trips.
// Slot for h_{t+3} is re-sentineled in step t's tail; the next step's
// __syncthreads (implicit vmcnt(0)) orders it before the h_{t+2} data store,
// and any writer of h_{t+3} must first consume h_{t+2} -> sentinel always
// lands before conflicting data. Ring reuses are disjoint under the skew
// bound (a WG computing step t implies all WGs stored h_t).
__global__ void __launch_bounds__(256, 1)
lstm_persistent(const float* __restrict__ x,     // [B,T,D]
                const float* __restrict__ Wx,    // [D,4H]
                const float* __restrict__ Wh,    // [H,4H]
                const float* __restrict__ bias,  // [4H] (i,f,g,o)
                float* __restrict__ y,           // [B,T,H]
                short* __restrict__ h_buf)       // ws: [DP][B][H] bf16 ring
{
    const int wg   = blockIdx.x;
    const int tid  = threadIdx.x;
    const int lane = tid & 63;
    const int wv   = tid >> 6;
    const int bt   = (wg >> 1) & 3;               // batch tile 0..3
    const int jt   = ((wg & 1) << 5) | (wg >> 3); // hidden tile 0..63
    const int j0   = jt * 16;

    const int c    = lane & 15;         // A-row (batch) / B-col within tile
    const int kblk = lane >> 4;         // k-block (8 contiguous k)
    const int b_a  = bt * 16 + c;       // global batch for A-frags
    const int kh0  = wv * 256;          // wave's K-slice of H
    const int kx0  = wv * 128;          // wave's K-slice of D

    __shared__ bf16x8 hw[4][4][8][64];  // 128 KB: [wv][gate][ks][lane]
    __shared__ float  gbuf[4][16][67];  // 17 KB partial-gate tiles

    // ---- prologue: h-weights -> LDS (each thread fills/reads its own slot)
#pragma unroll
    for (int g = 0; g < 4; ++g)
#pragma unroll
        for (int ks = 0; ks < 8; ++ks) {
            bf16x8 tf;
#pragma unroll
            for (int e = 0; e < 8; ++e)
                tf[e] = f2bf(Wh[(size_t)(kh0 + ks * 32 + kblk * 8 + e) * G4H
                                + g * H_ + j0 + c]);
            hw[wv][g][ks][lane] = tf;
        }

    // ---- x-weights -> registers (64 VGPRs), pinned vs rematerialization
    bf16x8 wxf[4][4];
#pragma unroll
    for (int g = 0; g < 4; ++g)
#pragma unroll
        for (int ks = 0; ks < 4; ++ks) {
            bf16x8 tf;
#pragma unroll
            for (int e = 0; e < 8; ++e)
                tf[e] = f2bf(Wx[(size_t)(kx0 + ks * 32 + kblk * 8 + e) * G4H
                                + g * H_ + j0 + c]);
            wxf[g][ks] = tf;
        }
#pragma unroll
    for (int g = 0; g < 4; ++g)
#pragma unroll
        for (int ks = 0; ks < 4; ++ks)
            asm volatile("" : "+v"(wxf[g][ks]));   // opaque: cannot re-load

    // ---- epilogue mapping: thread -> one (batch eb, hidden ej)
    const int eb = tid >> 4;
    const int ej = tid & 15;
    const float bi  = bias[0 * H_ + j0 + ej];
    const float bfv = bias[1 * H_ + j0 + ej];
    const float bg  = bias[2 * H_ + j0 + ej];
    const float bo  = bias[3 * H_ + j0 + ej];
    const int b_glob = bt * 16 + eb;
    const int j_glob = j0 + ej;

    float cstate = 0.0f;

    // ---- x-part for t=0 (h-independent)
    f32x4 accx[4] = {{0.f,0.f,0.f,0.f},{0.f,0.f,0.f,0.f},
                     {0.f,0.f,0.f,0.f},{0.f,0.f,0.f,0.f}};
    {
        const float* xr = x + ((size_t)b_a * T_ + 0) * D_ + kx0 + kblk * 8;
#pragma unroll
        for (int ks = 0; ks < 4; ++ks) {
            f32x4 lo = *(const f32x4*)(xr + ks * 32);
            f32x4 hi = *(const f32x4*)(xr + ks * 32 + 4);
            bf16x8 xa;
#pragma unroll
            for (int e = 0; e < 4; ++e) { xa[e] = f2bf(lo[e]); xa[e+4] = f2bf(hi[e]); }
#pragma unroll
            for (int g = 0; g < 4; ++g)
                accx[g] = __builtin_amdgcn_mfma_f32_16x16x32_bf16(xa, wxf[g][ks], accx[g], 0, 0, 0);
        }
    }

#pragma unroll 1
    for (int t = 0; t < T_; ++t) {
        // ---- poll h_t: each wave waits only ITS K-slice's 16 producers ----
        const unsigned long long* hq = (const unsigned long long*)
            (h_buf + (t & 3) * (B_ * H_) + (size_t)b_a * H_ + kh0 + kblk * 8);
        unsigned long long q[16];
        for (;;) {
#pragma unroll
            for (int ks = 0; ks < 8; ++ks) {
                q[2*ks]   = aload(hq + ks * 8);       // 32 shorts = 8 qwords apart
                q[2*ks+1] = aload(hq + ks * 8 + 1);
            }
            bool mine = true;
#pragma unroll
            for (int i = 0; i < 16; ++i) mine &= (q[i] != SENTQ);
            if (__all(mine)) break;
        }

        // ---- h MFMAs (weights from LDS, 4 chains) ----
#pragma unroll
        for (int ks = 0; ks < 8; ++ks) {
            union { unsigned long long qq[2]; bf16x8 v; } ua;
            ua.qq[0] = q[2*ks]; ua.qq[1] = q[2*ks+1];
            bf16x8 w0 = hw[wv][0][ks][lane];
            bf16x8 w1 = hw[wv][1][ks][lane];
            bf16x8 w2 = hw[wv][2][ks][lane];
            bf16x8 w3 = hw[wv][3][ks][lane];
            accx[0] = __builtin_amdgcn_mfma_f32_16x16x32_bf16(ua.v, w0, accx[0], 0, 0, 0);
            accx[1] = __builtin_amdgcn_mfma_f32_16x16x32_bf16(ua.v, w1, accx[1], 0, 0, 0);
            accx[2] = __builtin_amdgcn_mfma_f32_16x16x32_bf16(ua.v, w2, accx[2], 0, 0, 0);
            accx[3] = __builtin_amdgcn_mfma_f32_16x16x32_bf16(ua.v, w3, accx[3], 0, 0, 0);
        }

        // ---- partials -> LDS (D layout: col = lane&15, row = kblk*4 + r) ----
#pragma unroll
        for (int g = 0; g < 4; ++g)
#pragma unroll
            for (int r = 0; r < 4; ++r)
                gbuf[wv][kblk * 4 + r][g * 16 + c] = accx[g][r];
        // sync1: also drains (vmcnt 0) last step's tail stores -> orders the
        // re-sentinel of buf[(t+2)%4] before this step's h-data store.
        asm volatile("s_waitcnt vmcnt(0)" ::: "memory");
        __syncthreads();

        // ---- reduce 4 wave-partials + activations ----
        float gi = ((gbuf[0][eb][ 0+ej] + gbuf[1][eb][ 0+ej])
                  + (gbuf[2][eb][ 0+ej] + gbuf[3][eb][ 0+ej])) + bi;
        float gf = ((gbuf[0][eb][16+ej] + gbuf[1][eb][16+ej])
                  + (gbuf[2][eb][16+ej] + gbuf[3][eb][16+ej])) + bfv;
        float gg = ((gbuf[0][eb][32+ej] + gbuf[1][eb][32+ej])
                  + (gbuf[2][eb][32+ej] + gbuf[3][eb][32+ej])) + bg;
        float go = ((gbuf[0][eb][48+ej] + gbuf[1][eb][48+ej])
                  + (gbuf[2][eb][48+ej] + gbuf[3][eb][48+ej])) + bo;

        float I = sigmoid_f(gi);
        float F = sigmoid_f(gf);
        float G = tanh_f(gg);
        float O = sigmoid_f(go);
        cstate = F * cstate + I * G;
        float hval = O * tanh_f(cstate);

        // ---- h store = THE signal (packed 8B per 4 lanes, fire-and-forget) ----
        unsigned int mybf = (unsigned int)(unsigned short)f2bf(hval);
        unsigned int p01  = mybf | (((unsigned int)__shfl_xor((int)mybf, 1, 64)) << 16);
        unsigned int p23  = (unsigned int)__shfl_xor((int)p01, 2, 64);
        if ((t + 1 < T_) && (ej & 3) == 0) {
            unsigned long long pk = (unsigned long long)p01
                                  | ((unsigned long long)p23 << 32);
            unsigned long long* hp = (unsigned long long*)
                (h_buf + ((t + 1) & 3) * (B_ * H_) + (size_t)b_glob * H_ + j_glob);
            __hip_atomic_store(hp, pk, __ATOMIC_RELAXED, __HIP_MEMORY_SCOPE_AGENT);
        }
        // sync2: protect gbuf reuse (reads above vs next step's writes)
        __syncthreads();

        // ---- tail (off critical path): y, re-sentinel, next x-part ----
        y[((size_t)b_glob * T_ + t) * H_ + j_glob] = hval;   // 64B / 16 lanes

        // re-sentinel ring slot for h_{t+3} (old h_{t-1}, all consumers done)
        if (tid < 64) {
            int bb = bt * 16 + (tid >> 2);
            int jj = j0 + (tid & 3) * 4;
            unsigned long long* sp = (unsigned long long*)
                (h_buf + ((t + 3) & 3) * (B_ * H_) + (size_t)bb * H_ + jj);
            __hip_atomic_store(sp, SENTQ, __ATOMIC_RELAXED, __HIP_MEMORY_SCOPE_AGENT);
        }

#pragma unroll
        for (int g = 0; g < 4; ++g)
            accx[g] = (f32x4){0.f,0.f,0.f,0.f};
        if (t + 1 < T_) {
            const float* xr = x + ((size_t)b_a * T_ + (t + 1)) * D_ + kx0 + kblk * 8;
#pragma unroll
            for (int ks = 0; ks < 4; ++ks) {
                f32x4 lo = *(const f32x4*)(xr + ks * 32);
                f32x4 hi = *(const f32x4*)(xr + ks * 32 + 4);
                bf16x8 xa;
#pragma unroll
                for (int e = 0; e < 4; ++e) { xa[e] = f2bf(lo[e]); xa[e+4] = f2bf(hi[e]); }
#pragma unroll
                for (int g = 0; g < 4; ++g)
                    accx[g] = __builtin_amdgcn_mfma_f32_16x16x32_bf16(xa, wxf[g][ks], accx[g], 0, 0, 0);
            }
        }
    }
}

extern "C" void kernel_launch(void* const* d_in, const int* in_sizes, int n_in,
                              void* d_out, int out_size, void* d_ws, size_t ws_size,
                              hipStream_t stream)
{
    const float* x    = (const float*)d_in[0];
    const float* Wx   = (const float*)d_in[1];
    const float* Wh   = (const float*)d_in[2];
    const float* bias = (const float*)d_in[3];
    float* y = (float*)d_out;

    short* h_buf = (short*)d_ws;   // DP * B * H bf16 = 512 KB ring

    // Re-init the ring every call (replay-safe): buf0 = h_0 = zeros,
    // buf1..3 = sentinel. Pattern fill -> kernel, not memset.
    init_hbuf<<<dim3((DP * B_ * H_ / 2) / 256), dim3(256), 0, stream>>>(
        (unsigned int*)h_buf);

    lstm_persistent<<<dim3(NWG), dim3(256), 0, stream>>>(
        x, Wx, Wh, bias, y, h_buf);
}